// Round 6
// baseline (688.463 us; speedup 1.0000x reference)
//
#include <hip/hip_runtime.h>

typedef float vfloat4 __attribute__((ext_vector_type(4)));   // native vec for nt-store

// ---------------- CSR construction ----------------

// Counts edges per dst AND records each edge's arrival rank (atomicAdd return),
// so the fill pass needs no atomics at all.
__global__ void deg_kernel(const int* __restrict__ dst, int* __restrict__ deg,
                           int* __restrict__ rank, int E) {
    int e = blockIdx.x * 256 + threadIdx.x;
    if (e < E) rank[e] = atomicAdd(&deg[dst[e]], 1);
}

__global__ void dinv_kernel(const int* __restrict__ deg, float* __restrict__ dinv, int n) {
    int i = blockIdx.x * 256 + threadIdx.x;
    if (i < n) dinv[i] = rsqrtf((float)(deg[i] + 1));   // +1 self-loop; deg+1 >= 1
}

__global__ void scan_blocksum(const int* __restrict__ deg, int* __restrict__ bsum, int n) {
    int i = blockIdx.x * 256 + threadIdx.x;
    int v = (i < n) ? (deg[i] + 1) : 0;
    for (int off = 32; off > 0; off >>= 1) v += __shfl_down(v, off, 64);
    __shared__ int ws[4];
    if ((threadIdx.x & 63) == 0) ws[threadIdx.x >> 6] = v;
    __syncthreads();
    if (threadIdx.x == 0) bsum[blockIdx.x] = ws[0] + ws[1] + ws[2] + ws[3];
}

__global__ void scan_offsets(const int* __restrict__ bsum, int* __restrict__ boff, int nblk) {
    __shared__ int buf[256];
    int tid = threadIdx.x;
    int v = (tid < nblk) ? bsum[tid] : 0;
    buf[tid] = v;
    __syncthreads();
    for (int off = 1; off < 256; off <<= 1) {
        int t = (tid >= off) ? buf[tid - off] : 0;
        __syncthreads();
        buf[tid] += t;
        __syncthreads();
    }
    if (tid < nblk) boff[tid] = buf[tid] - v;   // exclusive
}

__global__ void scan_rowptr(const int* __restrict__ deg, const int* __restrict__ boff,
                            int* __restrict__ row_ptr, int n) {
    __shared__ int buf[256];
    int tid = threadIdx.x;
    int i = blockIdx.x * 256 + tid;
    int v = (i < n) ? (deg[i] + 1) : 0;
    buf[tid] = v;
    __syncthreads();
    for (int off = 1; off < 256; off <<= 1) {
        int t = (tid >= off) ? buf[tid - off] : 0;
        __syncthreads();
        buf[tid] += t;
        __syncthreads();
    }
    int excl = buf[tid] - v + boff[blockIdx.x];
    if (i < n) row_ptr[i] = excl;
    if (i == n - 1) row_ptr[n] = excl + v;
}

// Atomic-free fill: pos = row_ptr[dst] + 1 + rank (self-loop deterministically at slot 0).
__global__ void fill_kernel(const int* __restrict__ src, const int* __restrict__ dst,
                            const int* __restrict__ rank,
                            const int* __restrict__ row_ptr,
                            int* __restrict__ csr_src, int E, int n) {
    int e = blockIdx.x * 256 + threadIdx.x;
    if (e < E) {
        int s = src[e], d = dst[e];
        int pos = row_ptr[d] + 1 + rank[e];
        __builtin_nontemporal_store(s, &csr_src[pos]);
    } else if (e < E + n) {
        int s = e - E;
        __builtin_nontemporal_store(s, &csr_src[row_ptr[s]]);
    }
}

// ---------------- Aggregation: out[n] = dinv[n] * sum_s dinv[s] * in[s] ----------------
// Feature-slice partitioned for XCD-L2 locality: block b handles slice (b&7) of
// nodes (b>>3)*4.. (+wave). Blocks dispatch round-robin over the 8 XCDs, so each
// XCD's L2 only caches its 1/8 column slice of h (3.2 MB < 4 MiB).
// C=128: slice = 16 floats; 4 lanes/edge x 16 edge-groups per wave.
// C=64 : slice =  8 floats; 2 lanes/edge x 32 edge-groups per wave.

__device__ inline float4 xor_add4(float4 a, int m) {
    a.x += __shfl_xor(a.x, m, 64);
    a.y += __shfl_xor(a.y, m, 64);
    a.z += __shfl_xor(a.z, m, 64);
    a.w += __shfl_xor(a.w, m, 64);
    return a;
}

template<int C>
__global__ __launch_bounds__(256) void agg_slice(
        const float* __restrict__ in, float* __restrict__ out,
        const int* __restrict__ row_ptr, const int* __restrict__ csr_src,
        const float* __restrict__ dinv, int n) {
    int slice = blockIdx.x & 7;
    int node = (blockIdx.x >> 3) * 4 + (threadIdx.x >> 6);
    int lane = threadIdx.x & 63;
    if (node >= n) return;
    int beg = row_ptr[node], end = row_ptr[node + 1];
    const float4* in4 = (const float4*)in;
    vfloat4* out4 = (vfloat4*)out;

    if (C == 128) {
        int g = lane >> 2, col = lane & 3;   // 16 groups of 4 lanes; 64 B per edge
        float4 acc = make_float4(0.f, 0.f, 0.f, 0.f);
        for (int i = beg + g; i < end; i += 16) {
            int s = __builtin_nontemporal_load(&csr_src[i]);
            float w = dinv[s];
            float4 v = in4[(size_t)s * 32 + slice * 4 + col];
            acc.x = fmaf(w, v.x, acc.x); acc.y = fmaf(w, v.y, acc.y);
            acc.z = fmaf(w, v.z, acc.z); acc.w = fmaf(w, v.w, acc.w);
        }
        acc = xor_add4(acc, 4);
        acc = xor_add4(acc, 8);
        acc = xor_add4(acc, 16);
        acc = xor_add4(acc, 32);
        if (lane < 4) {
            float dn = dinv[node];
            vfloat4 o = { acc.x * dn, acc.y * dn, acc.z * dn, acc.w * dn };
            __builtin_nontemporal_store(o, &out4[(size_t)node * 32 + slice * 4 + lane]);
        }
    } else {  // C == 64
        int g = lane >> 1, col = lane & 1;   // 32 groups of 2 lanes; 32 B per edge
        float4 acc = make_float4(0.f, 0.f, 0.f, 0.f);
        for (int i = beg + g; i < end; i += 32) {
            int s = __builtin_nontemporal_load(&csr_src[i]);
            float w = dinv[s];
            float4 v = in4[(size_t)s * 16 + slice * 2 + col];
            acc.x = fmaf(w, v.x, acc.x); acc.y = fmaf(w, v.y, acc.y);
            acc.z = fmaf(w, v.z, acc.z); acc.w = fmaf(w, v.w, acc.w);
        }
        acc = xor_add4(acc, 2);
        acc = xor_add4(acc, 4);
        acc = xor_add4(acc, 8);
        acc = xor_add4(acc, 16);
        acc = xor_add4(acc, 32);
        if (lane < 2) {
            float dn = dinv[node];
            vfloat4 o = { acc.x * dn, acc.y * dn, acc.z * dn, acc.w * dn };
            __builtin_nontemporal_store(o, &out4[(size_t)node * 16 + slice * 2 + lane]);
        }
    }
}

// ---------------- GEMM + bias (+ReLU): [n,K] @ [K,128] ----------------

template<int K, bool RELU>
__global__ __launch_bounds__(256) void gemm_bias(
        const float* __restrict__ A, const float* __restrict__ W,
        const float* __restrict__ b, float* __restrict__ out, int n) {
    __shared__ float Ws[K * 128];
    __shared__ float As[32 * K];
    int tid = threadIdx.x;
    for (int i = tid * 4; i < K * 128; i += 256 * 4)
        *(float4*)&Ws[i] = *(const float4*)&W[i];
    int row0 = blockIdx.x * 32;
    for (int i = tid * 4; i < 32 * K; i += 256 * 4) {
        int r = i / K;
        int k = i - r * K;
        int gr = row0 + r;
        float4 v = make_float4(0.f, 0.f, 0.f, 0.f);
        if (gr < n) v = *(const float4*)&A[(size_t)gr * K + k];
        *(float4*)&As[i] = v;
    }
    __syncthreads();
    int tx = tid & 31;
    int ty = tid >> 5;
    float acc[4][4];
    float4 bv = *(const float4*)&b[tx * 4];
#pragma unroll
    for (int i = 0; i < 4; ++i) { acc[i][0] = bv.x; acc[i][1] = bv.y; acc[i][2] = bv.z; acc[i][3] = bv.w; }
    for (int k = 0; k < K; ++k) {
        float4 wv = *(const float4*)&Ws[k * 128 + tx * 4];
        float av[4];
#pragma unroll
        for (int i = 0; i < 4; ++i) av[i] = As[(ty * 4 + i) * K + k];
#pragma unroll
        for (int i = 0; i < 4; ++i) {
            acc[i][0] = fmaf(av[i], wv.x, acc[i][0]);
            acc[i][1] = fmaf(av[i], wv.y, acc[i][1]);
            acc[i][2] = fmaf(av[i], wv.z, acc[i][2]);
            acc[i][3] = fmaf(av[i], wv.w, acc[i][3]);
        }
    }
#pragma unroll
    for (int i = 0; i < 4; ++i) {
        int gr = row0 + ty * 4 + i;
        if (gr < n) {
            float4 o;
            o.x = RELU ? fmaxf(acc[i][0], 0.f) : acc[i][0];
            o.y = RELU ? fmaxf(acc[i][1], 0.f) : acc[i][1];
            o.z = RELU ? fmaxf(acc[i][2], 0.f) : acc[i][2];
            o.w = RELU ? fmaxf(acc[i][3], 0.f) : acc[i][3];
            *(float4*)&out[(size_t)gr * 128 + tx * 4] = o;
        }
    }
}

// ---------------- Pooling + head ----------------

// batch is sorted: gstart[g] = lower_bound(batch, g). No atomics, handles empty graphs.
__global__ void gstart_bs(const int* __restrict__ batch, int* __restrict__ gstart,
                          int n, int G) {
    int g = blockIdx.x * blockDim.x + threadIdx.x;
    if (g > G) return;
    int lo = 0, hi = n;
    while (lo < hi) {
        int mid = (lo + hi) >> 1;
        if (batch[mid] < g) lo = mid + 1; else hi = mid;
    }
    gstart[g] = lo;
}

__global__ void pool_kernel(const float* __restrict__ h, const int* __restrict__ gstart,
                            float* __restrict__ gout) {
    __shared__ float part[512];
    int g = blockIdx.x;
    int tid = threadIdx.x;
    int c = tid & 127, rs = tid >> 7;
    int beg = gstart[g], end = gstart[g + 1];
    float acc = 0.f;
    for (int nrow = beg + rs; nrow < end; nrow += 4)
        acc += h[(size_t)nrow * 128 + c];
    part[tid] = acc;
    __syncthreads();
    if (rs == 0) {
        float t = part[c] + part[c + 128] + part[c + 256] + part[c + 384];
        gout[g * 128 + c] = t / fmaxf((float)(end - beg), 1.f);
    }
}

__global__ void head_kernel(const float* __restrict__ g, const float* __restrict__ Wh,
                            const float* __restrict__ bh, float* __restrict__ out, int G) {
    int tid = blockIdx.x * blockDim.x + threadIdx.x;
    if (tid >= G * 8) return;
    int gi = tid >> 3, o = tid & 7;
    float acc = bh[o];
    for (int k = 0; k < 128; ++k)
        acc = fmaf(g[gi * 128 + k], Wh[k * 8 + o], acc);
    out[tid] = acc;
}

// ---------------- Launch ----------------

extern "C" void kernel_launch(void* const* d_in, const int* in_sizes, int n_in,
                              void* d_out, int out_size, void* d_ws, size_t ws_size,
                              hipStream_t stream) {
    const float* x  = (const float*)d_in[0];
    const float* W1 = (const float*)d_in[1];
    const float* b1 = (const float*)d_in[2];
    const float* W2 = (const float*)d_in[3];
    const float* b2 = (const float*)d_in[4];
    const float* W3 = (const float*)d_in[5];
    const float* b3 = (const float*)d_in[6];
    const float* Wh = (const float*)d_in[7];
    const float* bh = (const float*)d_in[8];
    const int* edge_index = (const int*)d_in[9];
    const int* batch = (const int*)d_in[10];
    (void)n_in; (void)ws_size;

    const int N = in_sizes[10];
    const int E = in_sizes[9] / 2;
    const int G = out_size / 8;
    const int* esrc = edge_index;
    const int* edst = edge_index + E;

    size_t off = 0;
    auto take = [&](size_t bytes) {
        void* p = (char*)d_ws + off;
        off += (bytes + 255) & ~(size_t)255;
        return p;
    };
    int*   deg      = (int*)take((size_t)N * 4);
    float* dinv     = (float*)take((size_t)N * 4);
    int*   row_ptr  = (int*)take((size_t)(N + 1) * 4);
    int*   rank     = (int*)take((size_t)E * 4);
    int*   csr_src  = (int*)take((size_t)(E + N) * 4);
    int*   bsum     = (int*)take(256 * 4);
    int*   boff     = (int*)take(256 * 4);
    int*   gstart   = (int*)take((size_t)(G + 1) * 4);
    float* gpool    = (float*)take((size_t)G * 128 * 4);
    float* bufA     = (float*)take((size_t)N * 128 * 4);
    float* bufB     = (float*)take((size_t)N * 128 * 4);

    int nblk = (N + 255) / 256;   // 196 for N=50000 (fits single-block scan_offsets)
    int agg_grid = 8 * ((N + 3) / 4);

    hipMemsetAsync(deg, 0, (size_t)N * 4, stream);

    deg_kernel<<<(E + 255) / 256, 256, 0, stream>>>(edst, deg, rank, E);
    dinv_kernel<<<nblk, 256, 0, stream>>>(deg, dinv, N);
    scan_blocksum<<<nblk, 256, 0, stream>>>(deg, bsum, N);
    scan_offsets<<<1, 256, 0, stream>>>(bsum, boff, nblk);
    scan_rowptr<<<nblk, 256, 0, stream>>>(deg, boff, row_ptr, N);
    fill_kernel<<<(E + N + 255) / 256, 256, 0, stream>>>(esrc, edst, rank, row_ptr, csr_src, E, N);

    // Layer 1: aggregate 64-wide input first (Agg(x)@W1 == Agg(x@W1)), then GEMM+bias+ReLU
    agg_slice<64><<<agg_grid, 256, 0, stream>>>(x, bufB, row_ptr, csr_src, dinv, N);
    gemm_bias<64, true><<<(N + 31) / 32, 256, 0, stream>>>(bufB, W1, b1, bufA, N);
    // Layer 2
    agg_slice<128><<<agg_grid, 256, 0, stream>>>(bufA, bufB, row_ptr, csr_src, dinv, N);
    gemm_bias<128, true><<<(N + 31) / 32, 256, 0, stream>>>(bufB, W2, b2, bufA, N);
    // Layer 3 (no ReLU)
    agg_slice<128><<<agg_grid, 256, 0, stream>>>(bufA, bufB, row_ptr, csr_src, dinv, N);
    gemm_bias<128, false><<<(N + 31) / 32, 256, 0, stream>>>(bufB, W3, b3, bufA, N);

    // Pool (batch is sorted -> contiguous per-graph row ranges) + head
    gstart_bs<<<1, 256, 0, stream>>>(batch, gstart, N, G);
    pool_kernel<<<G, 512, 0, stream>>>(bufA, gstart, gpool);
    head_kernel<<<(G * 8 + 255) / 256, 256, 0, stream>>>(gpool, Wh, bh, (float*)d_out, G);
}

// Round 7
// 327.714 us; speedup vs baseline: 2.1008x; 2.1008x over previous
//
#include <hip/hip_runtime.h>

typedef float vfloat4 __attribute__((ext_vector_type(4)));

__device__ inline unsigned short f2bf(float f) {        // RNE f32 -> bf16
    unsigned u = __float_as_uint(f);
    return (unsigned short)((u + 0x7fff + ((u >> 16) & 1)) >> 16);
}

// ---------------- CSR construction ----------------

// Counts edges per dst AND records each edge's arrival rank (atomicAdd return),
// so the fill pass needs no atomics at all.
__global__ void deg_kernel(const int* __restrict__ dst, int* __restrict__ deg,
                           int* __restrict__ rank, int E) {
    int e = blockIdx.x * 256 + threadIdx.x;
    if (e < E) rank[e] = atomicAdd(&deg[dst[e]], 1);
}

__global__ void dinv_kernel(const int* __restrict__ deg, float* __restrict__ dinv, int n) {
    int i = blockIdx.x * 256 + threadIdx.x;
    if (i < n) dinv[i] = rsqrtf((float)(deg[i] + 1));   // +1 self-loop; deg+1 >= 1
}

__global__ void scan_blocksum(const int* __restrict__ deg, int* __restrict__ bsum, int n) {
    int i = blockIdx.x * 256 + threadIdx.x;
    int v = (i < n) ? (deg[i] + 1) : 0;
    for (int off = 32; off > 0; off >>= 1) v += __shfl_down(v, off, 64);
    __shared__ int ws[4];
    if ((threadIdx.x & 63) == 0) ws[threadIdx.x >> 6] = v;
    __syncthreads();
    if (threadIdx.x == 0) bsum[blockIdx.x] = ws[0] + ws[1] + ws[2] + ws[3];
}

__global__ void scan_offsets(const int* __restrict__ bsum, int* __restrict__ boff, int nblk) {
    __shared__ int buf[256];
    int tid = threadIdx.x;
    int v = (tid < nblk) ? bsum[tid] : 0;
    buf[tid] = v;
    __syncthreads();
    for (int off = 1; off < 256; off <<= 1) {
        int t = (tid >= off) ? buf[tid - off] : 0;
        __syncthreads();
        buf[tid] += t;
        __syncthreads();
    }
    if (tid < nblk) boff[tid] = buf[tid] - v;   // exclusive
}

__global__ void scan_rowptr(const int* __restrict__ deg, const int* __restrict__ boff,
                            int* __restrict__ row_ptr, int n) {
    __shared__ int buf[256];
    int tid = threadIdx.x;
    int i = blockIdx.x * 256 + tid;
    int v = (i < n) ? (deg[i] + 1) : 0;
    buf[tid] = v;
    __syncthreads();
    for (int off = 1; off < 256; off <<= 1) {
        int t = (tid >= off) ? buf[tid - off] : 0;
        __syncthreads();
        buf[tid] += t;
        __syncthreads();
    }
    int excl = buf[tid] - v + boff[blockIdx.x];
    if (i < n) row_ptr[i] = excl;
    if (i == n - 1) row_ptr[n] = excl + v;
}

// Atomic-free fill: pos = row_ptr[dst] + 1 + rank (self-loop deterministically at slot 0).
__global__ void fill_kernel(const int* __restrict__ src, const int* __restrict__ dst,
                            const int* __restrict__ rank,
                            const int* __restrict__ row_ptr,
                            int* __restrict__ csr_src, int E, int n) {
    int e = blockIdx.x * 256 + threadIdx.x;
    if (e < E) {
        int s = src[e], d = dst[e];
        int pos = row_ptr[d] + 1 + rank[e];
        __builtin_nontemporal_store(s, &csr_src[pos]);
    } else if (e < E + n) {
        int s = e - E;
        __builtin_nontemporal_store(s, &csr_src[row_ptr[s]]);
    }
}

// ---------------- Aggregation: out[n] = dinv[n] * sum_s dinv[s] * in[s] ----------------

// fp32, C=64 (layer 1, reads input x). Quarter-waves, 2-deep unroll -> 8 rows in flight.
__global__ __launch_bounds__(256) void agg_f32_64(
        const float* __restrict__ in, float* __restrict__ out,
        const int* __restrict__ row_ptr, const int* __restrict__ csr_src,
        const float* __restrict__ dinv, int n) {
    int node = blockIdx.x * 4 + (threadIdx.x >> 6);
    int lane = threadIdx.x & 63;
    if (node >= n) return;
    int beg = row_ptr[node], end = row_ptr[node + 1];
    const float4* in4 = (const float4*)in;
    int q = lane >> 4;
    int col = lane & 15;
    float4 acc = make_float4(0.f, 0.f, 0.f, 0.f);
    int i = beg + q;
    for (; i + 4 < end; i += 8) {
        int s0 = csr_src[i];
        int s1 = csr_src[i + 4];
        float4 v0 = in4[(size_t)s0 * 16 + col];
        float4 v1 = in4[(size_t)s1 * 16 + col];
        float w0 = dinv[s0], w1 = dinv[s1];
        acc.x = fmaf(w0, v0.x, acc.x); acc.y = fmaf(w0, v0.y, acc.y);
        acc.z = fmaf(w0, v0.z, acc.z); acc.w = fmaf(w0, v0.w, acc.w);
        acc.x = fmaf(w1, v1.x, acc.x); acc.y = fmaf(w1, v1.y, acc.y);
        acc.z = fmaf(w1, v1.z, acc.z); acc.w = fmaf(w1, v1.w, acc.w);
    }
    if (i < end) {
        int s = csr_src[i];
        float w = dinv[s];
        float4 v = in4[(size_t)s * 16 + col];
        acc.x = fmaf(w, v.x, acc.x); acc.y = fmaf(w, v.y, acc.y);
        acc.z = fmaf(w, v.z, acc.z); acc.w = fmaf(w, v.w, acc.w);
    }
#pragma unroll
    for (int m = 16; m <= 32; m <<= 1) {
        acc.x += __shfl_xor(acc.x, m, 64);
        acc.y += __shfl_xor(acc.y, m, 64);
        acc.z += __shfl_xor(acc.z, m, 64);
        acc.w += __shfl_xor(acc.w, m, 64);
    }
    if (q == 0) {
        float dn = dinv[node];
        ((float4*)out)[(size_t)node * 16 + col] =
            make_float4(acc.x * dn, acc.y * dn, acc.z * dn, acc.w * dn);
    }
}

// bf16 gather, C=128 (layers 2,3). Row = 256 B; quarter-wave x 16 B = 1 edge,
// 2-deep unroll -> 8 rows in flight/wave. fp32 accumulate, fp32 out.
__device__ inline void bf8_fma(uint4 a, float w, float* acc) {
#pragma unroll
    for (int j = 0; j < 4; ++j) {
        unsigned u = ((const unsigned*)&a)[j];
        acc[2 * j]     = fmaf(w, __uint_as_float(u << 16), acc[2 * j]);
        acc[2 * j + 1] = fmaf(w, __uint_as_float(u & 0xffff0000u), acc[2 * j + 1]);
    }
}

__global__ __launch_bounds__(256) void agg_bf16_128(
        const unsigned short* __restrict__ in, float* __restrict__ out,
        const int* __restrict__ row_ptr, const int* __restrict__ csr_src,
        const float* __restrict__ dinv, int n) {
    int node = blockIdx.x * 4 + (threadIdx.x >> 6);
    int lane = threadIdx.x & 63;
    if (node >= n) return;
    int beg = row_ptr[node], end = row_ptr[node + 1];
    const uint4* in4 = (const uint4*)in;       // 8 bf16 per uint4; row = 16 uint4
    int q = lane >> 4;
    int col = lane & 15;
    float acc[8] = {0.f, 0.f, 0.f, 0.f, 0.f, 0.f, 0.f, 0.f};
    int i = beg + q;
    for (; i + 4 < end; i += 8) {
        int s0 = csr_src[i];
        int s1 = csr_src[i + 4];
        uint4 a = in4[(size_t)s0 * 16 + col];
        uint4 b = in4[(size_t)s1 * 16 + col];
        float w0 = dinv[s0], w1 = dinv[s1];
        bf8_fma(a, w0, acc);
        bf8_fma(b, w1, acc);
    }
    if (i < end) {
        int s = csr_src[i];
        uint4 a = in4[(size_t)s * 16 + col];
        bf8_fma(a, dinv[s], acc);
    }
#pragma unroll
    for (int j = 0; j < 8; ++j) {
        acc[j] += __shfl_xor(acc[j], 16, 64);
        acc[j] += __shfl_xor(acc[j], 32, 64);
    }
    if (q == 0) {
        float dn = dinv[node];
        float4* o4 = (float4*)out;
        o4[(size_t)node * 32 + col * 2] =
            make_float4(acc[0] * dn, acc[1] * dn, acc[2] * dn, acc[3] * dn);
        o4[(size_t)node * 32 + col * 2 + 1] =
            make_float4(acc[4] * dn, acc[5] * dn, acc[6] * dn, acc[7] * dn);
    }
}

// ---------------- GEMM + bias (+ReLU): [n,K] @ [K,128], optional bf16 output ----------------

template<int K, bool RELU, bool BF16OUT>
__global__ __launch_bounds__(256) void gemm_bias(
        const float* __restrict__ A, const float* __restrict__ W,
        const float* __restrict__ b, void* __restrict__ outp, int n) {
    __shared__ float Ws[K * 128];
    __shared__ float As[32 * K];
    int tid = threadIdx.x;
    for (int i = tid * 4; i < K * 128; i += 256 * 4)
        *(float4*)&Ws[i] = *(const float4*)&W[i];
    int row0 = blockIdx.x * 32;
    for (int i = tid * 4; i < 32 * K; i += 256 * 4) {
        int r = i / K;
        int k = i - r * K;
        int gr = row0 + r;
        float4 v = make_float4(0.f, 0.f, 0.f, 0.f);
        if (gr < n) v = *(const float4*)&A[(size_t)gr * K + k];
        *(float4*)&As[i] = v;
    }
    __syncthreads();
    int tx = tid & 31;
    int ty = tid >> 5;
    float acc[4][4];
    float4 bv = *(const float4*)&b[tx * 4];
#pragma unroll
    for (int i = 0; i < 4; ++i) { acc[i][0] = bv.x; acc[i][1] = bv.y; acc[i][2] = bv.z; acc[i][3] = bv.w; }
    for (int k = 0; k < K; ++k) {
        float4 wv = *(const float4*)&Ws[k * 128 + tx * 4];
        float av[4];
#pragma unroll
        for (int i = 0; i < 4; ++i) av[i] = As[(ty * 4 + i) * K + k];
#pragma unroll
        for (int i = 0; i < 4; ++i) {
            acc[i][0] = fmaf(av[i], wv.x, acc[i][0]);
            acc[i][1] = fmaf(av[i], wv.y, acc[i][1]);
            acc[i][2] = fmaf(av[i], wv.z, acc[i][2]);
            acc[i][3] = fmaf(av[i], wv.w, acc[i][3]);
        }
    }
#pragma unroll
    for (int i = 0; i < 4; ++i) {
        int gr = row0 + ty * 4 + i;
        if (gr < n) {
            float r0 = RELU ? fmaxf(acc[i][0], 0.f) : acc[i][0];
            float r1 = RELU ? fmaxf(acc[i][1], 0.f) : acc[i][1];
            float r2 = RELU ? fmaxf(acc[i][2], 0.f) : acc[i][2];
            float r3 = RELU ? fmaxf(acc[i][3], 0.f) : acc[i][3];
            if (BF16OUT) {
                ushort4 o;
                o.x = f2bf(r0); o.y = f2bf(r1); o.z = f2bf(r2); o.w = f2bf(r3);
                *(ushort4*)((unsigned short*)outp + (size_t)gr * 128 + tx * 4) = o;
            } else {
                *(float4*)((float*)outp + (size_t)gr * 128 + tx * 4) =
                    make_float4(r0, r1, r2, r3);
            }
        }
    }
}

// ---------------- Pooling + head ----------------

// batch is sorted: gstart[g] = lower_bound(batch, g). No atomics, handles empty graphs.
__global__ void gstart_bs(const int* __restrict__ batch, int* __restrict__ gstart,
                          int n, int G) {
    int g = blockIdx.x * blockDim.x + threadIdx.x;
    if (g > G) return;
    int lo = 0, hi = n;
    while (lo < hi) {
        int mid = (lo + hi) >> 1;
        if (batch[mid] < g) lo = mid + 1; else hi = mid;
    }
    gstart[g] = lo;
}

__global__ void pool_kernel(const float* __restrict__ h, const int* __restrict__ gstart,
                            float* __restrict__ gout) {
    __shared__ float part[512];
    int g = blockIdx.x;
    int tid = threadIdx.x;
    int c = tid & 127, rs = tid >> 7;
    int beg = gstart[g], end = gstart[g + 1];
    float acc = 0.f;
    for (int nrow = beg + rs; nrow < end; nrow += 4)
        acc += h[(size_t)nrow * 128 + c];
    part[tid] = acc;
    __syncthreads();
    if (rs == 0) {
        float t = part[c] + part[c + 128] + part[c + 256] + part[c + 384];
        gout[g * 128 + c] = t / fmaxf((float)(end - beg), 1.f);
    }
}

__global__ void head_kernel(const float* __restrict__ g, const float* __restrict__ Wh,
                            const float* __restrict__ bh, float* __restrict__ out, int G) {
    int tid = blockIdx.x * blockDim.x + threadIdx.x;
    if (tid >= G * 8) return;
    int gi = tid >> 3, o = tid & 7;
    float acc = bh[o];
    for (int k = 0; k < 128; ++k)
        acc = fmaf(g[gi * 128 + k], Wh[k * 8 + o], acc);
    out[tid] = acc;
}

// ---------------- Launch ----------------

extern "C" void kernel_launch(void* const* d_in, const int* in_sizes, int n_in,
                              void* d_out, int out_size, void* d_ws, size_t ws_size,
                              hipStream_t stream) {
    const float* x  = (const float*)d_in[0];
    const float* W1 = (const float*)d_in[1];
    const float* b1 = (const float*)d_in[2];
    const float* W2 = (const float*)d_in[3];
    const float* b2 = (const float*)d_in[4];
    const float* W3 = (const float*)d_in[5];
    const float* b3 = (const float*)d_in[6];
    const float* Wh = (const float*)d_in[7];
    const float* bh = (const float*)d_in[8];
    const int* edge_index = (const int*)d_in[9];
    const int* batch = (const int*)d_in[10];
    (void)n_in; (void)ws_size;

    const int N = in_sizes[10];
    const int E = in_sizes[9] / 2;
    const int G = out_size / 8;
    const int* esrc = edge_index;
    const int* edst = edge_index + E;

    size_t off = 0;
    auto take = [&](size_t bytes) {
        void* p = (char*)d_ws + off;
        off += (bytes + 255) & ~(size_t)255;
        return p;
    };
    int*   deg      = (int*)take((size_t)N * 4);
    float* dinv     = (float*)take((size_t)N * 4);
    int*   row_ptr  = (int*)take((size_t)(N + 1) * 4);
    int*   rank     = (int*)take((size_t)E * 4);
    int*   csr_src  = (int*)take((size_t)(E + N) * 4);
    int*   bsum     = (int*)take(256 * 4);
    int*   boff     = (int*)take(256 * 4);
    int*   gstart   = (int*)take((size_t)(G + 1) * 4);
    float* gpool    = (float*)take((size_t)G * 128 * 4);
    unsigned short* h16 = (unsigned short*)take((size_t)N * 128 * 2);
    float* bufA     = (float*)take((size_t)N * 128 * 4);
    float* bufB     = (float*)take((size_t)N * 128 * 4);

    int nblk = (N + 255) / 256;   // 196 for N=50000 (fits single-block scan_offsets)

    hipMemsetAsync(deg, 0, (size_t)N * 4, stream);

    deg_kernel<<<(E + 255) / 256, 256, 0, stream>>>(edst, deg, rank, E);
    dinv_kernel<<<nblk, 256, 0, stream>>>(deg, dinv, N);
    scan_blocksum<<<nblk, 256, 0, stream>>>(deg, bsum, N);
    scan_offsets<<<1, 256, 0, stream>>>(bsum, boff, nblk);
    scan_rowptr<<<nblk, 256, 0, stream>>>(deg, boff, row_ptr, N);
    fill_kernel<<<(E + N + 255) / 256, 256, 0, stream>>>(esrc, edst, rank, row_ptr, csr_src, E, N);

    // Layer 1: aggregate 64-wide fp32 input (Agg(x)@W1 == Agg(x@W1)), GEMM writes bf16 h1
    agg_f32_64<<<(N + 3) / 4, 256, 0, stream>>>(x, bufB, row_ptr, csr_src, dinv, N);
    gemm_bias<64, true, true><<<(N + 31) / 32, 256, 0, stream>>>(bufB, W1, b1, h16, N);
    // Layer 2: bf16 gather, GEMM writes bf16 h2
    agg_bf16_128<<<(N + 3) / 4, 256, 0, stream>>>(h16, bufB, row_ptr, csr_src, dinv, N);
    gemm_bias<128, true, true><<<(N + 31) / 32, 256, 0, stream>>>(bufB, W2, b2, h16, N);
    // Layer 3: bf16 gather, GEMM writes fp32 (no ReLU)
    agg_bf16_128<<<(N + 3) / 4, 256, 0, stream>>>(h16, bufB, row_ptr, csr_src, dinv, N);
    gemm_bias<128, false, false><<<(N + 31) / 32, 256, 0, stream>>>(bufB, W3, b3, bufA, N);

    // Pool (batch is sorted -> contiguous per-graph row ranges) + head
    gstart_bs<<<1, 256, 0, stream>>>(batch, gstart, N, G);
    pool_kernel<<<G, 512, 0, stream>>>(bufA, gstart, gpool);
    head_kernel<<<(G * 8 + 255) / 256, 256, 0, stream>>>(gpool, Wh, bh, (float*)d_out, G);
}

// Round 8
// 288.150 us; speedup vs baseline: 2.3893x; 1.1373x over previous
//
#include <hip/hip_runtime.h>

__device__ inline unsigned short f2bf(float f) {        // RNE f32 -> bf16
    unsigned u = __float_as_uint(f);
    return (unsigned short)((u + 0x7fff + ((u >> 16) & 1)) >> 16);
}

// ---------------- CSR construction ----------------

// Counts edges per dst AND records each edge's arrival rank (atomicAdd return),
// so the fill pass needs no atomics at all.
__global__ void deg_kernel(const int* __restrict__ dst, int* __restrict__ deg,
                           int* __restrict__ rank, int E) {
    int e = blockIdx.x * 256 + threadIdx.x;
    if (e < E) rank[e] = atomicAdd(&deg[dst[e]], 1);
}

__global__ void dinv_kernel(const int* __restrict__ deg, float* __restrict__ dinv, int n) {
    int i = blockIdx.x * 256 + threadIdx.x;
    if (i < n) dinv[i] = rsqrtf((float)(deg[i] + 1));   // +1 self-loop; deg+1 >= 1
}

__global__ void scan_blocksum(const int* __restrict__ deg, int* __restrict__ bsum, int n) {
    int i = blockIdx.x * 256 + threadIdx.x;
    int v = (i < n) ? (deg[i] + 1) : 0;
    for (int off = 32; off > 0; off >>= 1) v += __shfl_down(v, off, 64);
    __shared__ int ws[4];
    if ((threadIdx.x & 63) == 0) ws[threadIdx.x >> 6] = v;
    __syncthreads();
    if (threadIdx.x == 0) bsum[blockIdx.x] = ws[0] + ws[1] + ws[2] + ws[3];
}

__global__ void scan_offsets(const int* __restrict__ bsum, int* __restrict__ boff, int nblk) {
    __shared__ int buf[256];
    int tid = threadIdx.x;
    int v = (tid < nblk) ? bsum[tid] : 0;
    buf[tid] = v;
    __syncthreads();
    for (int off = 1; off < 256; off <<= 1) {
        int t = (tid >= off) ? buf[tid - off] : 0;
        __syncthreads();
        buf[tid] += t;
        __syncthreads();
    }
    if (tid < nblk) boff[tid] = buf[tid] - v;   // exclusive
}

__global__ void scan_rowptr(const int* __restrict__ deg, const int* __restrict__ boff,
                            int* __restrict__ row_ptr, int n) {
    __shared__ int buf[256];
    int tid = threadIdx.x;
    int i = blockIdx.x * 256 + tid;
    int v = (i < n) ? (deg[i] + 1) : 0;
    buf[tid] = v;
    __syncthreads();
    for (int off = 1; off < 256; off <<= 1) {
        int t = (tid >= off) ? buf[tid - off] : 0;
        __syncthreads();
        buf[tid] += t;
        __syncthreads();
    }
    int excl = buf[tid] - v + boff[blockIdx.x];
    if (i < n) row_ptr[i] = excl;
    if (i == n - 1) row_ptr[n] = excl + v;
}

// Atomic-free fill: pos = row_ptr[dst] + 1 + rank (self-loop deterministically at slot 0).
__global__ void fill_kernel(const int* __restrict__ src, const int* __restrict__ dst,
                            const int* __restrict__ rank,
                            const int* __restrict__ row_ptr,
                            int* __restrict__ csr_src, int E, int n) {
    int e = blockIdx.x * 256 + threadIdx.x;
    if (e < E) {
        int s = src[e], d = dst[e];
        int pos = row_ptr[d] + 1 + rank[e];
        __builtin_nontemporal_store(s, &csr_src[pos]);
    } else if (e < E + n) {
        int s = e - E;
        __builtin_nontemporal_store(s, &csr_src[row_ptr[s]]);
    }
}

// Convert x (N*64 fp32) to bf16 once; layer-1 gather then moves half the bytes.
__global__ void x2bf_kernel(const float* __restrict__ x, unsigned* __restrict__ x16,
                            int total8) {   // total8 = N*64/8
    int i = blockIdx.x * 256 + threadIdx.x;
    if (i >= total8) return;
    const float4* x4 = (const float4*)x;
    float4 a = x4[i * 2], b = x4[i * 2 + 1];
    uint4 o;
    o.x = (unsigned)f2bf(a.x) | ((unsigned)f2bf(a.y) << 16);
    o.y = (unsigned)f2bf(a.z) | ((unsigned)f2bf(a.w) << 16);
    o.z = (unsigned)f2bf(b.x) | ((unsigned)f2bf(b.y) << 16);
    o.w = (unsigned)f2bf(b.z) | ((unsigned)f2bf(b.w) << 16);
    ((uint4*)x16)[i] = o;
}

// ---------------- Aggregation: out[n] = dinv[n] * sum_s dinv[s] * in[s] ----------------
// bf16 gather rows, fp32 accumulate, fp32 out (feeds GEMM).

__device__ inline void bf8_fma(uint4 a, float w, float* acc) {
#pragma unroll
    for (int j = 0; j < 4; ++j) {
        unsigned u = ((const unsigned*)&a)[j];
        acc[2 * j]     = fmaf(w, __uint_as_float(u << 16), acc[2 * j]);
        acc[2 * j + 1] = fmaf(w, __uint_as_float(u & 0xffff0000u), acc[2 * j + 1]);
    }
}

// C=64: row = 128 B = 8 uint4; 8 lanes/edge x 8 groups, 2-deep unroll -> 16 rows in flight.
__global__ __launch_bounds__(256) void agg_bf16_64(
        const unsigned short* __restrict__ in, float* __restrict__ out,
        const int* __restrict__ row_ptr, const int* __restrict__ csr_src,
        const float* __restrict__ dinv, int n) {
    int node = blockIdx.x * 4 + (threadIdx.x >> 6);
    int lane = threadIdx.x & 63;
    if (node >= n) return;
    int beg = row_ptr[node], end = row_ptr[node + 1];
    const uint4* in4 = (const uint4*)in;       // row = 8 uint4
    int g = lane >> 3;
    int col = lane & 7;
    float acc[8] = {0.f, 0.f, 0.f, 0.f, 0.f, 0.f, 0.f, 0.f};
    int i = beg + g;
    for (; i + 8 < end; i += 16) {
        int s0 = csr_src[i];
        int s1 = csr_src[i + 8];
        uint4 a = in4[(size_t)s0 * 8 + col];
        uint4 b = in4[(size_t)s1 * 8 + col];
        float w0 = dinv[s0], w1 = dinv[s1];
        bf8_fma(a, w0, acc);
        bf8_fma(b, w1, acc);
    }
    if (i < end) {
        int s = csr_src[i];
        uint4 a = in4[(size_t)s * 8 + col];
        bf8_fma(a, dinv[s], acc);
    }
#pragma unroll
    for (int j = 0; j < 8; ++j) {
        acc[j] += __shfl_xor(acc[j], 8, 64);
        acc[j] += __shfl_xor(acc[j], 16, 64);
        acc[j] += __shfl_xor(acc[j], 32, 64);
    }
    if (g == 0) {
        float dn = dinv[node];
        float4* o4 = (float4*)out;              // row = 16 float4; lane col covers 2
        o4[(size_t)node * 16 + col * 2] =
            make_float4(acc[0] * dn, acc[1] * dn, acc[2] * dn, acc[3] * dn);
        o4[(size_t)node * 16 + col * 2 + 1] =
            make_float4(acc[4] * dn, acc[5] * dn, acc[6] * dn, acc[7] * dn);
    }
}

// C=128: row = 256 B = 16 uint4; 16 lanes/edge x 4 groups, 2-deep unroll -> 8 rows in flight.
__global__ __launch_bounds__(256) void agg_bf16_128(
        const unsigned short* __restrict__ in, float* __restrict__ out,
        const int* __restrict__ row_ptr, const int* __restrict__ csr_src,
        const float* __restrict__ dinv, int n) {
    int node = blockIdx.x * 4 + (threadIdx.x >> 6);
    int lane = threadIdx.x & 63;
    if (node >= n) return;
    int beg = row_ptr[node], end = row_ptr[node + 1];
    const uint4* in4 = (const uint4*)in;       // row = 16 uint4
    int q = lane >> 4;
    int col = lane & 15;
    float acc[8] = {0.f, 0.f, 0.f, 0.f, 0.f, 0.f, 0.f, 0.f};
    int i = beg + q;
    for (; i + 4 < end; i += 8) {
        int s0 = csr_src[i];
        int s1 = csr_src[i + 4];
        uint4 a = in4[(size_t)s0 * 16 + col];
        uint4 b = in4[(size_t)s1 * 16 + col];
        float w0 = dinv[s0], w1 = dinv[s1];
        bf8_fma(a, w0, acc);
        bf8_fma(b, w1, acc);
    }
    if (i < end) {
        int s = csr_src[i];
        uint4 a = in4[(size_t)s * 16 + col];
        bf8_fma(a, dinv[s], acc);
    }
#pragma unroll
    for (int j = 0; j < 8; ++j) {
        acc[j] += __shfl_xor(acc[j], 16, 64);
        acc[j] += __shfl_xor(acc[j], 32, 64);
    }
    if (q == 0) {
        float dn = dinv[node];
        float4* o4 = (float4*)out;
        o4[(size_t)node * 32 + col * 2] =
            make_float4(acc[0] * dn, acc[1] * dn, acc[2] * dn, acc[3] * dn);
        o4[(size_t)node * 32 + col * 2 + 1] =
            make_float4(acc[4] * dn, acc[5] * dn, acc[6] * dn, acc[7] * dn);
    }
}

// ---------------- GEMM + bias (+ReLU): [n,K] @ [K,128], optional bf16 output ----------------

template<int K, bool RELU, bool BF16OUT>
__global__ __launch_bounds__(256) void gemm_bias(
        const float* __restrict__ A, const float* __restrict__ W,
        const float* __restrict__ b, void* __restrict__ outp, int n) {
    __shared__ float Ws[K * 128];
    __shared__ float As[32 * K];
    int tid = threadIdx.x;
    for (int i = tid * 4; i < K * 128; i += 256 * 4)
        *(float4*)&Ws[i] = *(const float4*)&W[i];
    int row0 = blockIdx.x * 32;
    for (int i = tid * 4; i < 32 * K; i += 256 * 4) {
        int r = i / K;
        int k = i - r * K;
        int gr = row0 + r;
        float4 v = make_float4(0.f, 0.f, 0.f, 0.f);
        if (gr < n) v = *(const float4*)&A[(size_t)gr * K + k];
        *(float4*)&As[i] = v;
    }
    __syncthreads();
    int tx = tid & 31;
    int ty = tid >> 5;
    float acc[4][4];
    float4 bv = *(const float4*)&b[tx * 4];
#pragma unroll
    for (int i = 0; i < 4; ++i) { acc[i][0] = bv.x; acc[i][1] = bv.y; acc[i][2] = bv.z; acc[i][3] = bv.w; }
    for (int k = 0; k < K; ++k) {
        float4 wv = *(const float4*)&Ws[k * 128 + tx * 4];
        float av[4];
#pragma unroll
        for (int i = 0; i < 4; ++i) av[i] = As[(ty * 4 + i) * K + k];
#pragma unroll
        for (int i = 0; i < 4; ++i) {
            acc[i][0] = fmaf(av[i], wv.x, acc[i][0]);
            acc[i][1] = fmaf(av[i], wv.y, acc[i][1]);
            acc[i][2] = fmaf(av[i], wv.z, acc[i][2]);
            acc[i][3] = fmaf(av[i], wv.w, acc[i][3]);
        }
    }
#pragma unroll
    for (int i = 0; i < 4; ++i) {
        int gr = row0 + ty * 4 + i;
        if (gr < n) {
            float r0 = RELU ? fmaxf(acc[i][0], 0.f) : acc[i][0];
            float r1 = RELU ? fmaxf(acc[i][1], 0.f) : acc[i][1];
            float r2 = RELU ? fmaxf(acc[i][2], 0.f) : acc[i][2];
            float r3 = RELU ? fmaxf(acc[i][3], 0.f) : acc[i][3];
            if (BF16OUT) {
                ushort4 o;
                o.x = f2bf(r0); o.y = f2bf(r1); o.z = f2bf(r2); o.w = f2bf(r3);
                *(ushort4*)((unsigned short*)outp + (size_t)gr * 128 + tx * 4) = o;
            } else {
                *(float4*)((float*)outp + (size_t)gr * 128 + tx * 4) =
                    make_float4(r0, r1, r2, r3);
            }
        }
    }
}

// ---------------- Pooling + head ----------------

// batch is sorted: gstart[g] = lower_bound(batch, g). No atomics, handles empty graphs.
__global__ void gstart_bs(const int* __restrict__ batch, int* __restrict__ gstart,
                          int n, int G) {
    int g = blockIdx.x * blockDim.x + threadIdx.x;
    if (g > G) return;
    int lo = 0, hi = n;
    while (lo < hi) {
        int mid = (lo + hi) >> 1;
        if (batch[mid] < g) lo = mid + 1; else hi = mid;
    }
    gstart[g] = lo;
}

// Two-stage mean pool (deterministic, no float atomics).
// Stage 1: block (g, sp) sums its row-chunk -> part[(g*16+sp)*128 + c].
#define PSPLIT 16
__global__ __launch_bounds__(256) void pool_part(
        const float* __restrict__ h, const int* __restrict__ gstart,
        float* __restrict__ part) {
    int g = blockIdx.x >> 4, sp = blockIdx.x & (PSPLIT - 1);
    int tid = threadIdx.x;
    int c = tid & 127, rs = tid >> 7;
    int beg = gstart[g], end = gstart[g + 1];
    int len = end - beg;
    int chunk = (len + PSPLIT - 1) >> 4;
    int r0 = beg + sp * chunk;
    int r1 = min(r0 + chunk, end);
    float acc = 0.f;
    for (int r = r0 + rs; r < r1; r += 2)
        acc += h[(size_t)r * 128 + c];
    __shared__ float buf[256];
    buf[tid] = acc;
    __syncthreads();
    if (rs == 0)
        part[(size_t)blockIdx.x * 128 + c] = buf[c] + buf[c + 128];
}

// Stage 2: reduce the 16 partials, divide by count.
__global__ __launch_bounds__(128) void pool_final(
        const float* __restrict__ part, const int* __restrict__ gstart,
        float* __restrict__ gout) {
    int g = blockIdx.x;
    int c = threadIdx.x;
    float acc = 0.f;
#pragma unroll
    for (int sp = 0; sp < PSPLIT; ++sp)
        acc += part[((size_t)g * PSPLIT + sp) * 128 + c];
    int cnt = gstart[g + 1] - gstart[g];
    gout[g * 128 + c] = acc / fmaxf((float)cnt, 1.f);
}

__global__ void head_kernel(const float* __restrict__ g, const float* __restrict__ Wh,
                            const float* __restrict__ bh, float* __restrict__ out, int G) {
    int tid = blockIdx.x * blockDim.x + threadIdx.x;
    if (tid >= G * 8) return;
    int gi = tid >> 3, o = tid & 7;
    float acc = bh[o];
    for (int k = 0; k < 128; ++k)
        acc = fmaf(g[gi * 128 + k], Wh[k * 8 + o], acc);
    out[tid] = acc;
}

// ---------------- Launch ----------------

extern "C" void kernel_launch(void* const* d_in, const int* in_sizes, int n_in,
                              void* d_out, int out_size, void* d_ws, size_t ws_size,
                              hipStream_t stream) {
    const float* x  = (const float*)d_in[0];
    const float* W1 = (const float*)d_in[1];
    const float* b1 = (const float*)d_in[2];
    const float* W2 = (const float*)d_in[3];
    const float* b2 = (const float*)d_in[4];
    const float* W3 = (const float*)d_in[5];
    const float* b3 = (const float*)d_in[6];
    const float* Wh = (const float*)d_in[7];
    const float* bh = (const float*)d_in[8];
    const int* edge_index = (const int*)d_in[9];
    const int* batch = (const int*)d_in[10];
    (void)n_in; (void)ws_size;

    const int N = in_sizes[10];
    const int E = in_sizes[9] / 2;
    const int G = out_size / 8;
    const int* esrc = edge_index;
    const int* edst = edge_index + E;

    size_t off = 0;
    auto take = [&](size_t bytes) {
        void* p = (char*)d_ws + off;
        off += (bytes + 255) & ~(size_t)255;
        return p;
    };
    int*   deg      = (int*)take((size_t)N * 4);
    float* dinv     = (float*)take((size_t)N * 4);
    int*   row_ptr  = (int*)take((size_t)(N + 1) * 4);
    int*   rank     = (int*)take((size_t)E * 4);
    int*   csr_src  = (int*)take((size_t)(E + N) * 4);
    int*   bsum     = (int*)take(256 * 4);
    int*   boff     = (int*)take(256 * 4);
    int*   gstart   = (int*)take((size_t)(G + 1) * 4);
    float* part     = (float*)take((size_t)G * PSPLIT * 128 * 4);
    float* gpool    = (float*)take((size_t)G * 128 * 4);
    unsigned short* x16 = (unsigned short*)take((size_t)N * 64 * 2);
    unsigned short* h16 = (unsigned short*)take((size_t)N * 128 * 2);
    float* bufA     = (float*)take((size_t)N * 128 * 4);
    float* bufB     = (float*)take((size_t)N * 128 * 4);

    int nblk = (N + 255) / 256;   // 196 for N=50000 (fits single-block scan_offsets)

    hipMemsetAsync(deg, 0, (size_t)N * 4, stream);

    deg_kernel<<<(E + 255) / 256, 256, 0, stream>>>(edst, deg, rank, E);
    dinv_kernel<<<nblk, 256, 0, stream>>>(deg, dinv, N);
    scan_blocksum<<<nblk, 256, 0, stream>>>(deg, bsum, N);
    scan_offsets<<<1, 256, 0, stream>>>(bsum, boff, nblk);
    scan_rowptr<<<nblk, 256, 0, stream>>>(deg, boff, row_ptr, N);
    fill_kernel<<<(E + N + 255) / 256, 256, 0, stream>>>(esrc, edst, rank, row_ptr, csr_src, E, N);
    x2bf_kernel<<<(N * 64 / 8 + 255) / 256, 256, 0, stream>>>(x, (unsigned*)x16, N * 64 / 8);

    // Layer 1: bf16 gather of x (Agg(x)@W1 == Agg(x@W1)), GEMM writes bf16 h1
    agg_bf16_64<<<(N + 3) / 4, 256, 0, stream>>>(x16, bufB, row_ptr, csr_src, dinv, N);
    gemm_bias<64, true, true><<<(N + 31) / 32, 256, 0, stream>>>(bufB, W1, b1, h16, N);
    // Layer 2: bf16 gather, GEMM writes bf16 h2
    agg_bf16_128<<<(N + 3) / 4, 256, 0, stream>>>(h16, bufB, row_ptr, csr_src, dinv, N);
    gemm_bias<128, true, true><<<(N + 31) / 32, 256, 0, stream>>>(bufB, W2, b2, h16, N);
    // Layer 3: bf16 gather, GEMM writes fp32 (no ReLU)
    agg_bf16_128<<<(N + 3) / 4, 256, 0, stream>>>(h16, bufB, row_ptr, csr_src, dinv, N);
    gemm_bias<128, false, false><<<(N + 31) / 32, 256, 0, stream>>>(bufB, W3, b3, bufA, N);

    // Pool (batch sorted -> contiguous ranges): two-stage, then head
    gstart_bs<<<1, 256, 0, stream>>>(batch, gstart, N, G);
    pool_part<<<G * PSPLIT, 256, 0, stream>>>(bufA, gstart, part);
    pool_final<<<G, 128, 0, stream>>>(part, gstart, gpool);
    head_kernel<<<(G * 8 + 255) / 256, 256, 0, stream>>>(gpool, Wh, bh, (float*)d_out, G);
}

// Round 9
// 260.460 us; speedup vs baseline: 2.6433x; 1.1063x over previous
//
#include <hip/hip_runtime.h>

typedef short bf8_t __attribute__((ext_vector_type(8)));   // 8 bf16 in 4 VGPRs
typedef float f32x4 __attribute__((ext_vector_type(4)));

__device__ inline unsigned short f2bf(float f) {        // RNE f32 -> bf16
    unsigned u = __float_as_uint(f);
    return (unsigned short)((u + 0x7fff + ((u >> 16) & 1)) >> 16);
}

// ---------------- CSR construction ----------------

__global__ void deg_kernel(const int* __restrict__ dst, int* __restrict__ deg,
                           int* __restrict__ rank, int E) {
    int e = blockIdx.x * 256 + threadIdx.x;
    if (e < E) rank[e] = atomicAdd(&deg[dst[e]], 1);
}

__global__ void dinv_kernel(const int* __restrict__ deg, float* __restrict__ dinv, int n) {
    int i = blockIdx.x * 256 + threadIdx.x;
    if (i < n) dinv[i] = rsqrtf((float)(deg[i] + 1));   // +1 self-loop; deg+1 >= 1
}

__global__ void scan_blocksum(const int* __restrict__ deg, int* __restrict__ bsum, int n) {
    int i = blockIdx.x * 256 + threadIdx.x;
    int v = (i < n) ? (deg[i] + 1) : 0;
    for (int off = 32; off > 0; off >>= 1) v += __shfl_down(v, off, 64);
    __shared__ int ws[4];
    if ((threadIdx.x & 63) == 0) ws[threadIdx.x >> 6] = v;
    __syncthreads();
    if (threadIdx.x == 0) bsum[blockIdx.x] = ws[0] + ws[1] + ws[2] + ws[3];
}

__global__ void scan_offsets(const int* __restrict__ bsum, int* __restrict__ boff, int nblk) {
    __shared__ int buf[256];
    int tid = threadIdx.x;
    int v = (tid < nblk) ? bsum[tid] : 0;
    buf[tid] = v;
    __syncthreads();
    for (int off = 1; off < 256; off <<= 1) {
        int t = (tid >= off) ? buf[tid - off] : 0;
        __syncthreads();
        buf[tid] += t;
        __syncthreads();
    }
    if (tid < nblk) boff[tid] = buf[tid] - v;   // exclusive
}

__global__ void scan_rowptr(const int* __restrict__ deg, const int* __restrict__ boff,
                            int* __restrict__ row_ptr, int n) {
    __shared__ int buf[256];
    int tid = threadIdx.x;
    int i = blockIdx.x * 256 + tid;
    int v = (i < n) ? (deg[i] + 1) : 0;
    buf[tid] = v;
    __syncthreads();
    for (int off = 1; off < 256; off <<= 1) {
        int t = (tid >= off) ? buf[tid - off] : 0;
        __syncthreads();
        buf[tid] += t;
        __syncthreads();
    }
    int excl = buf[tid] - v + boff[blockIdx.x];
    if (i < n) row_ptr[i] = excl;
    if (i == n - 1) row_ptr[n] = excl + v;
}

// Atomic-free fill: pos = row_ptr[dst] + 1 + rank (self-loop deterministically at slot 0).
__global__ void fill_kernel(const int* __restrict__ src, const int* __restrict__ dst,
                            const int* __restrict__ rank,
                            const int* __restrict__ row_ptr,
                            int* __restrict__ csr_src, int E, int n) {
    int e = blockIdx.x * 256 + threadIdx.x;
    if (e < E) {
        int s = src[e], d = dst[e];
        int pos = row_ptr[d] + 1 + rank[e];
        __builtin_nontemporal_store(s, &csr_src[pos]);
    } else if (e < E + n) {
        int s = e - E;
        __builtin_nontemporal_store(s, &csr_src[row_ptr[s]]);
    }
}

// Convert x (N*64 fp32) to bf16 once.
__global__ void x2bf_kernel(const float* __restrict__ x, unsigned* __restrict__ x16,
                            int total8) {   // total8 = N*64/8
    int i = blockIdx.x * 256 + threadIdx.x;
    if (i >= total8) return;
    const float4* x4 = (const float4*)x;
    float4 a = x4[i * 2], b = x4[i * 2 + 1];
    uint4 o;
    o.x = (unsigned)f2bf(a.x) | ((unsigned)f2bf(a.y) << 16);
    o.y = (unsigned)f2bf(a.z) | ((unsigned)f2bf(a.w) << 16);
    o.z = (unsigned)f2bf(b.x) | ((unsigned)f2bf(b.y) << 16);
    o.w = (unsigned)f2bf(b.z) | ((unsigned)f2bf(b.w) << 16);
    ((uint4*)x16)[i] = o;
}

// W [K x Ncols] fp32 -> W^T [Ncols x K] bf16 (tiny, L2-resident).
__global__ void wt_kernel(const float* __restrict__ W, unsigned short* __restrict__ Wt,
                          int K, int Ncols) {
    int i = blockIdx.x * 256 + threadIdx.x;
    if (i >= K * Ncols) return;
    int nn = i / K, k = i - nn * K;
    Wt[i] = f2bf(W[k * Ncols + nn]);
}

// ---------------- Aggregation: out[n] = dinv[n]*sum dinv[s]*in[s]; bf16 in, bf16 out ----------------

__device__ inline void bf8_fma(uint4 a, float w, float* acc) {
#pragma unroll
    for (int j = 0; j < 4; ++j) {
        unsigned u = ((const unsigned*)&a)[j];
        acc[2 * j]     = fmaf(w, __uint_as_float(u << 16), acc[2 * j]);
        acc[2 * j + 1] = fmaf(w, __uint_as_float(u & 0xffff0000u), acc[2 * j + 1]);
    }
}

__device__ inline uint4 pack_bf8(const float* v, float dn) {
    uint4 o;
    o.x = (unsigned)f2bf(v[0] * dn) | ((unsigned)f2bf(v[1] * dn) << 16);
    o.y = (unsigned)f2bf(v[2] * dn) | ((unsigned)f2bf(v[3] * dn) << 16);
    o.z = (unsigned)f2bf(v[4] * dn) | ((unsigned)f2bf(v[5] * dn) << 16);
    o.w = (unsigned)f2bf(v[6] * dn) | ((unsigned)f2bf(v[7] * dn) << 16);
    return o;
}

// C=64: row = 128 B = 8 uint4; 8 lanes/edge x 8 groups, 2-deep unroll -> 16 rows in flight.
__global__ __launch_bounds__(256) void agg_bf16_64(
        const unsigned short* __restrict__ in, unsigned short* __restrict__ out,
        const int* __restrict__ row_ptr, const int* __restrict__ csr_src,
        const float* __restrict__ dinv, int n) {
    int node = blockIdx.x * 4 + (threadIdx.x >> 6);
    int lane = threadIdx.x & 63;
    if (node >= n) return;
    int beg = row_ptr[node], end = row_ptr[node + 1];
    const uint4* in4 = (const uint4*)in;       // row = 8 uint4
    int g = lane >> 3;
    int col = lane & 7;
    float acc[8] = {0.f, 0.f, 0.f, 0.f, 0.f, 0.f, 0.f, 0.f};
    int i = beg + g;
    for (; i + 8 < end; i += 16) {
        int s0 = csr_src[i];
        int s1 = csr_src[i + 8];
        uint4 a = in4[(size_t)s0 * 8 + col];
        uint4 b = in4[(size_t)s1 * 8 + col];
        float w0 = dinv[s0], w1 = dinv[s1];
        bf8_fma(a, w0, acc);
        bf8_fma(b, w1, acc);
    }
    if (i < end) {
        int s = csr_src[i];
        uint4 a = in4[(size_t)s * 8 + col];
        bf8_fma(a, dinv[s], acc);
    }
#pragma unroll
    for (int j = 0; j < 8; ++j) {
        acc[j] += __shfl_xor(acc[j], 8, 64);
        acc[j] += __shfl_xor(acc[j], 16, 64);
        acc[j] += __shfl_xor(acc[j], 32, 64);
    }
    if (g == 0)
        ((uint4*)out)[(size_t)node * 8 + col] = pack_bf8(acc, dinv[node]);
}

// C=128: row = 256 B = 16 uint4; 16 lanes/edge x 4 groups, 2-deep unroll -> 8 rows in flight.
__global__ __launch_bounds__(256) void agg_bf16_128(
        const unsigned short* __restrict__ in, unsigned short* __restrict__ out,
        const int* __restrict__ row_ptr, const int* __restrict__ csr_src,
        const float* __restrict__ dinv, int n) {
    int node = blockIdx.x * 4 + (threadIdx.x >> 6);
    int lane = threadIdx.x & 63;
    if (node >= n) return;
    int beg = row_ptr[node], end = row_ptr[node + 1];
    const uint4* in4 = (const uint4*)in;       // row = 16 uint4
    int q = lane >> 4;
    int col = lane & 15;
    float acc[8] = {0.f, 0.f, 0.f, 0.f, 0.f, 0.f, 0.f, 0.f};
    int i = beg + q;
    for (; i + 4 < end; i += 8) {
        int s0 = csr_src[i];
        int s1 = csr_src[i + 4];
        uint4 a = in4[(size_t)s0 * 16 + col];
        uint4 b = in4[(size_t)s1 * 16 + col];
        float w0 = dinv[s0], w1 = dinv[s1];
        bf8_fma(a, w0, acc);
        bf8_fma(b, w1, acc);
    }
    if (i < end) {
        int s = csr_src[i];
        uint4 a = in4[(size_t)s * 16 + col];
        bf8_fma(a, dinv[s], acc);
    }
#pragma unroll
    for (int j = 0; j < 8; ++j) {
        acc[j] += __shfl_xor(acc[j], 16, 64);
        acc[j] += __shfl_xor(acc[j], 32, 64);
    }
    if (q == 0)
        ((uint4*)out)[(size_t)node * 16 + col] = pack_bf8(acc, dinv[node]);
}

// ---------------- MFMA GEMM: [n,K]bf16 @ W^T[128,K]bf16 + bias (+ReLU) ----------------
// 16x16x32 bf16 MFMA. Wave-pair per 16-row tile: wave ch=0 -> cols 0-63, ch=1 -> 64-127.
// A frag: lane holds row=lane&15, k=(lane>>4)*8..+7 (16 B load). B in registers.
// C/D: col=lane&15, row=(lane>>4)*4+reg (m89-verified).

template<int K, bool RELU, bool BF16OUT>
__global__ __launch_bounds__(256) void mfma_gemm(
        const unsigned short* __restrict__ A16, const unsigned short* __restrict__ Wt16,
        const float* __restrict__ bias, void* __restrict__ outp, int n) {
    constexpr int KS = K / 32;
    int w = threadIdx.x >> 6;
    int lane = threadIdx.x & 63;
    int tile = blockIdx.x * 2 + (w >> 1);      // 16-row tile index
    int ch = w & 1;                            // column half
    int row0 = tile * 16;
    if (row0 >= n) return;
    int lr = lane & 15, lk = lane >> 4;

    bf8_t B[4][KS];
#pragma unroll
    for (int f = 0; f < 4; ++f) {
        int col = ch * 64 + f * 16 + lr;
#pragma unroll
        for (int ks = 0; ks < KS; ++ks)
            B[f][ks] = *reinterpret_cast<const bf8_t*>(&Wt16[(size_t)col * K + ks * 32 + lk * 8]);
    }

    int arow = row0 + lr;
    if (arow >= n) arow = n - 1;
    f32x4 acc[4] = {};
#pragma unroll
    for (int ks = 0; ks < KS; ++ks) {
        bf8_t a = *reinterpret_cast<const bf8_t*>(&A16[(size_t)arow * K + ks * 32 + lk * 8]);
#pragma unroll
        for (int f = 0; f < 4; ++f)
            acc[f] = __builtin_amdgcn_mfma_f32_16x16x32_bf16(a, B[f][ks], acc[f], 0, 0, 0);
    }

#pragma unroll
    for (int f = 0; f < 4; ++f) {
        int col = ch * 64 + f * 16 + lr;
        float bv = bias[col];
#pragma unroll
        for (int r = 0; r < 4; ++r) {
            int row = row0 + lk * 4 + r;
            if (row < n) {
                float v = acc[f][r] + bv;
                if (RELU) v = fmaxf(v, 0.f);
                if (BF16OUT)
                    ((unsigned short*)outp)[(size_t)row * 128 + col] = f2bf(v);
                else
                    ((float*)outp)[(size_t)row * 128 + col] = v;
            }
        }
    }
}

// ---------------- Pooling + head ----------------

__global__ void gstart_bs(const int* __restrict__ batch, int* __restrict__ gstart,
                          int n, int G) {
    int g = blockIdx.x * blockDim.x + threadIdx.x;
    if (g > G) return;
    int lo = 0, hi = n;
    while (lo < hi) {
        int mid = (lo + hi) >> 1;
        if (batch[mid] < g) lo = mid + 1; else hi = mid;
    }
    gstart[g] = lo;
}

#define PSPLIT 16
__global__ __launch_bounds__(256) void pool_part(
        const float* __restrict__ h, const int* __restrict__ gstart,
        float* __restrict__ part) {
    int g = blockIdx.x >> 4, sp = blockIdx.x & (PSPLIT - 1);
    int tid = threadIdx.x;
    int c = tid & 127, rs = tid >> 7;
    int beg = gstart[g], end = gstart[g + 1];
    int len = end - beg;
    int chunk = (len + PSPLIT - 1) >> 4;
    int r0 = beg + sp * chunk;
    int r1 = min(r0 + chunk, end);
    float acc = 0.f;
    for (int r = r0 + rs; r < r1; r += 2)
        acc += h[(size_t)r * 128 + c];
    __shared__ float buf[256];
    buf[tid] = acc;
    __syncthreads();
    if (rs == 0)
        part[(size_t)blockIdx.x * 128 + c] = buf[c] + buf[c + 128];
}

__global__ __launch_bounds__(128) void pool_final(
        const float* __restrict__ part, const int* __restrict__ gstart,
        float* __restrict__ gout) {
    int g = blockIdx.x;
    int c = threadIdx.x;
    float acc = 0.f;
#pragma unroll
    for (int sp = 0; sp < PSPLIT; ++sp)
        acc += part[((size_t)g * PSPLIT + sp) * 128 + c];
    int cnt = gstart[g + 1] - gstart[g];
    gout[g * 128 + c] = acc / fmaxf((float)cnt, 1.f);
}

__global__ void head_kernel(const float* __restrict__ g, const float* __restrict__ Wh,
                            const float* __restrict__ bh, float* __restrict__ out, int G) {
    int tid = blockIdx.x * blockDim.x + threadIdx.x;
    if (tid >= G * 8) return;
    int gi = tid >> 3, o = tid & 7;
    float acc = bh[o];
    for (int k = 0; k < 128; ++k)
        acc = fmaf(g[gi * 128 + k], Wh[k * 8 + o], acc);
    out[tid] = acc;
}

// ---------------- Launch ----------------

extern "C" void kernel_launch(void* const* d_in, const int* in_sizes, int n_in,
                              void* d_out, int out_size, void* d_ws, size_t ws_size,
                              hipStream_t stream) {
    const float* x  = (const float*)d_in[0];
    const float* W1 = (const float*)d_in[1];
    const float* b1 = (const float*)d_in[2];
    const float* W2 = (const float*)d_in[3];
    const float* b2 = (const float*)d_in[4];
    const float* W3 = (const float*)d_in[5];
    const float* b3 = (const float*)d_in[6];
    const float* Wh = (const float*)d_in[7];
    const float* bh = (const float*)d_in[8];
    const int* edge_index = (const int*)d_in[9];
    const int* batch = (const int*)d_in[10];
    (void)n_in; (void)ws_size;

    const int N = in_sizes[10];
    const int E = in_sizes[9] / 2;
    const int G = out_size / 8;
    const int* esrc = edge_index;
    const int* edst = edge_index + E;

    size_t off = 0;
    auto take = [&](size_t bytes) {
        void* p = (char*)d_ws + off;
        off += (bytes + 255) & ~(size_t)255;
        return p;
    };
    int*   deg      = (int*)take((size_t)N * 4);
    float* dinv     = (float*)take((size_t)N * 4);
    int*   row_ptr  = (int*)take((size_t)(N + 1) * 4);
    int*   rank     = (int*)take((size_t)E * 4);
    int*   csr_src  = (int*)take((size_t)(E + N) * 4);
    int*   bsum     = (int*)take(256 * 4);
    int*   boff     = (int*)take(256 * 4);
    int*   gstart   = (int*)take((size_t)(G + 1) * 4);
    float* part     = (float*)take((size_t)G * PSPLIT * 128 * 4);
    float* gpool    = (float*)take((size_t)G * 128 * 4);
    unsigned short* x16  = (unsigned short*)take((size_t)N * 64 * 2);
    unsigned short* a64  = (unsigned short*)take((size_t)N * 64 * 2);
    unsigned short* a128 = (unsigned short*)take((size_t)N * 128 * 2);
    unsigned short* h16  = (unsigned short*)take((size_t)N * 128 * 2);
    unsigned short* Wt1  = (unsigned short*)take((size_t)128 * 64 * 2);
    unsigned short* Wt2  = (unsigned short*)take((size_t)128 * 128 * 2);
    unsigned short* Wt3  = (unsigned short*)take((size_t)128 * 128 * 2);
    float* bufA     = (float*)take((size_t)N * 128 * 4);

    int nblk = (N + 255) / 256;
    int gemm_grid = ((N + 15) / 16 + 1) / 2;   // 2 row-tiles per block

    hipMemsetAsync(deg, 0, (size_t)N * 4, stream);

    deg_kernel<<<(E + 255) / 256, 256, 0, stream>>>(edst, deg, rank, E);
    dinv_kernel<<<nblk, 256, 0, stream>>>(deg, dinv, N);
    scan_blocksum<<<nblk, 256, 0, stream>>>(deg, bsum, N);
    scan_offsets<<<1, 256, 0, stream>>>(bsum, boff, nblk);
    scan_rowptr<<<nblk, 256, 0, stream>>>(deg, boff, row_ptr, N);
    fill_kernel<<<(E + N + 255) / 256, 256, 0, stream>>>(esrc, edst, rank, row_ptr, csr_src, E, N);
    x2bf_kernel<<<(N * 64 / 8 + 255) / 256, 256, 0, stream>>>(x, (unsigned*)x16, N * 64 / 8);
    wt_kernel<<<(64 * 128 + 255) / 256, 256, 0, stream>>>(W1, Wt1, 64, 128);
    wt_kernel<<<(128 * 128 + 255) / 256, 256, 0, stream>>>(W2, Wt2, 128, 128);
    wt_kernel<<<(128 * 128 + 255) / 256, 256, 0, stream>>>(W3, Wt3, 128, 128);

    // Layer 1: bf16 gather of x (Agg(x)@W1 == Agg(x@W1)), MFMA GEMM -> bf16 h1
    agg_bf16_64<<<(N + 3) / 4, 256, 0, stream>>>(x16, a64, row_ptr, csr_src, dinv, N);
    mfma_gemm<64, true, true><<<gemm_grid, 256, 0, stream>>>(a64, Wt1, b1, h16, N);
    // Layer 2
    agg_bf16_128<<<(N + 3) / 4, 256, 0, stream>>>(h16, a128, row_ptr, csr_src, dinv, N);
    mfma_gemm<128, true, true><<<gemm_grid, 256, 0, stream>>>(a128, Wt2, b2, h16, N);
    // Layer 3 (no ReLU, fp32 out)
    agg_bf16_128<<<(N + 3) / 4, 256, 0, stream>>>(h16, a128, row_ptr, csr_src, dinv, N);
    mfma_gemm<128, false, false><<<gemm_grid, 256, 0, stream>>>(a128, Wt3, b3, bufA, N);

    // Pool (batch sorted -> contiguous ranges): two-stage, then head
    gstart_bs<<<1, 256, 0, stream>>>(batch, gstart, N, G);
    pool_part<<<G * PSPLIT, 256, 0, stream>>>(bufA, gstart, part);
    pool_final<<<G, 128, 0, stream>>>(part, gstart, gpool);
    head_kernel<<<(G * 8 + 255) / 256, 256, 0, stream>>>(gpool, Wh, bh, (float*)d_out, G);
}

// Round 10
// 248.824 us; speedup vs baseline: 2.7669x; 1.0468x over previous
//
#include <hip/hip_runtime.h>

typedef short bf8_t __attribute__((ext_vector_type(8)));   // 8 bf16 in 4 VGPRs
typedef float f32x4 __attribute__((ext_vector_type(4)));

__device__ inline unsigned short f2bf(float f) {        // RNE f32 -> bf16
    unsigned u = __float_as_uint(f);
    return (unsigned short)((u + 0x7fff + ((u >> 16) & 1)) >> 16);
}

// ---------------- CSR construction ----------------

__global__ void deg_kernel(const int* __restrict__ dst, int* __restrict__ deg,
                           int* __restrict__ rank, int E) {
    int e = blockIdx.x * 256 + threadIdx.x;
    if (e < E) rank[e] = atomicAdd(&deg[dst[e]], 1);
}

// block sums of (deg+1) for rowptr scan; also emits dinv = rsqrt(deg+1)
__global__ void scan_blocksum(const int* __restrict__ deg, int* __restrict__ bsum,
                              float* __restrict__ dinv, int n) {
    int i = blockIdx.x * 256 + threadIdx.x;
    int d = (i < n) ? (deg[i] + 1) : 0;
    if (i < n) dinv[i] = rsqrtf((float)d);
    int v = d;
    for (int off = 32; off > 0; off >>= 1) v += __shfl_down(v, off, 64);
    __shared__ int ws[4];
    if ((threadIdx.x & 63) == 0) ws[threadIdx.x >> 6] = v;
    __syncthreads();
    if (threadIdx.x == 0) bsum[blockIdx.x] = ws[0] + ws[1] + ws[2] + ws[3];
}

__global__ void scan_offsets(const int* __restrict__ bsum, int* __restrict__ boff, int nblk) {
    __shared__ int buf[256];
    int tid = threadIdx.x;
    int v = (tid < nblk) ? bsum[tid] : 0;
    buf[tid] = v;
    __syncthreads();
    for (int off = 1; off < 256; off <<= 1) {
        int t = (tid >= off) ? buf[tid - off] : 0;
        __syncthreads();
        buf[tid] += t;
        __syncthreads();
    }
    if (tid < nblk) boff[tid] = buf[tid] - v;   // exclusive
}

__global__ void scan_rowptr(const int* __restrict__ deg, const int* __restrict__ boff,
                            int* __restrict__ row_ptr, int n) {
    __shared__ int buf[256];
    int tid = threadIdx.x;
    int i = blockIdx.x * 256 + tid;
    int v = (i < n) ? (deg[i] + 1) : 0;
    buf[tid] = v;
    __syncthreads();
    for (int off = 1; off < 256; off <<= 1) {
        int t = (tid >= off) ? buf[tid - off] : 0;
        __syncthreads();
        buf[tid] += t;
        __syncthreads();
    }
    int excl = buf[tid] - v + boff[blockIdx.x];
    if (i < n) row_ptr[i] = excl;
    if (i == n - 1) row_ptr[n] = excl + v;
}

// Atomic-free fill: pos = row_ptr[dst] + 1 + rank (self-loop deterministically at slot 0).
__global__ void fill_kernel(const int* __restrict__ src, const int* __restrict__ dst,
                            const int* __restrict__ rank,
                            const int* __restrict__ row_ptr,
                            int* __restrict__ csr_src, int E, int n) {
    int e = blockIdx.x * 256 + threadIdx.x;
    if (e < E) {
        int s = src[e], d = dst[e];
        int pos = row_ptr[d] + 1 + rank[e];
        __builtin_nontemporal_store(s, &csr_src[pos]);
    } else if (e < E + n) {
        int s = e - E;
        __builtin_nontemporal_store(s, &csr_src[row_ptr[s]]);
    }
}

// Convert x (N*64 fp32) to bf16 once.
__global__ void x2bf_kernel(const float* __restrict__ x, unsigned* __restrict__ x16,
                            int total8) {   // total8 = N*64/8
    int i = blockIdx.x * 256 + threadIdx.x;
    if (i >= total8) return;
    const float4* x4 = (const float4*)x;
    float4 a = x4[i * 2], b = x4[i * 2 + 1];
    uint4 o;
    o.x = (unsigned)f2bf(a.x) | ((unsigned)f2bf(a.y) << 16);
    o.y = (unsigned)f2bf(a.z) | ((unsigned)f2bf(a.w) << 16);
    o.z = (unsigned)f2bf(b.x) | ((unsigned)f2bf(b.y) << 16);
    o.w = (unsigned)f2bf(b.z) | ((unsigned)f2bf(b.w) << 16);
    ((uint4*)x16)[i] = o;
}

// All three W [K x 128] fp32 -> W^T [128 x K] bf16, one launch (40960 elems).
__global__ void wt_all(const float* __restrict__ W1, const float* __restrict__ W2,
                       const float* __restrict__ W3,
                       unsigned short* __restrict__ Wt1, unsigned short* __restrict__ Wt2,
                       unsigned short* __restrict__ Wt3) {
    int i = blockIdx.x * 256 + threadIdx.x;
    if (i < 8192) {                       // W1: K=64
        int nn = i / 64, k = i - nn * 64;
        Wt1[i] = f2bf(W1[k * 128 + nn]);
    } else if (i < 24576) {               // W2: K=128
        int j = i - 8192;
        int nn = j / 128, k = j - nn * 128;
        Wt2[j] = f2bf(W2[k * 128 + nn]);
    } else if (i < 40960) {               // W3: K=128
        int j = i - 24576;
        int nn = j / 128, k = j - nn * 128;
        Wt3[j] = f2bf(W3[k * 128 + nn]);
    }
}

// ---------------- Fused aggregate + MFMA GEMM ----------------
// out[node] = (dinv[node] * sum_s dinv[s]*in[s]) @ W^T + bias, optional ReLU.
// Block = 16 nodes, 4 waves. Wave w aggregates LDS rows w*4..w*4+3 (bf16, XOR-swizzled),
// then computes output cols w*32..w*32+31 via 16x16x32 bf16 MFMA.
// Operand order: mfma(W_frag, row_frag) so lane's 4 acc regs = 4 consecutive out cols
// (m89: D row = A-operand free index, D col = B-operand free index = lane&15).

__device__ inline void bf8_fma(uint4 a, float w, float* acc) {
#pragma unroll
    for (int j = 0; j < 4; ++j) {
        unsigned u = ((const unsigned*)&a)[j];
        acc[2 * j]     = fmaf(w, __uint_as_float(u << 16), acc[2 * j]);
        acc[2 * j + 1] = fmaf(w, __uint_as_float(u & 0xffff0000u), acc[2 * j + 1]);
    }
}

__device__ inline uint4 pack_bf8(const float* v, float dn) {
    uint4 o;
    o.x = (unsigned)f2bf(v[0] * dn) | ((unsigned)f2bf(v[1] * dn) << 16);
    o.y = (unsigned)f2bf(v[2] * dn) | ((unsigned)f2bf(v[3] * dn) << 16);
    o.z = (unsigned)f2bf(v[4] * dn) | ((unsigned)f2bf(v[5] * dn) << 16);
    o.w = (unsigned)f2bf(v[6] * dn) | ((unsigned)f2bf(v[7] * dn) << 16);
    return o;
}

template<int K, bool RELU, bool BF16OUT>
__global__ __launch_bounds__(256) void agg_gemm(
        const unsigned short* __restrict__ in, const unsigned short* __restrict__ Wt16,
        const float* __restrict__ bias, void* __restrict__ outp,
        const int* __restrict__ row_ptr, const int* __restrict__ csr_src,
        const float* __restrict__ dinv, int n) {
    constexpr int KS = K / 32;
    __shared__ unsigned short As[16 * K];
    int w = threadIdx.x >> 6, lane = threadIdx.x & 63;
    int base = blockIdx.x * 16;
    int lr = lane & 15, lk = lane >> 4;

    // Preload W frags (cols w*32..+31) before gather for latency overlap.
    bf8_t B[2][KS];
#pragma unroll
    for (int f = 0; f < 2; ++f) {
        int col = w * 32 + f * 16 + lr;
#pragma unroll
        for (int ks = 0; ks < KS; ++ks)
            B[f][ks] = *reinterpret_cast<const bf8_t*>(&Wt16[(size_t)col * K + ks * 32 + lk * 8]);
    }

    const uint4* in4 = (const uint4*)in;
    for (int nd = 0; nd < 4; ++nd) {
        int row = w * 4 + nd;
        int node = base + row;
        float acc[8] = {0.f, 0.f, 0.f, 0.f, 0.f, 0.f, 0.f, 0.f};
        if (node < n) {
            int beg = row_ptr[node], end = row_ptr[node + 1];
            if (K == 128) {          // row = 16 uint4; 16 lanes/edge, 2-deep unroll
                int col = lane & 15;
                int i = beg + (lane >> 4);
                for (; i + 4 < end; i += 8) {
                    int s0 = csr_src[i], s1 = csr_src[i + 4];
                    uint4 a = in4[(size_t)s0 * 16 + col];
                    uint4 b = in4[(size_t)s1 * 16 + col];
                    float w0 = dinv[s0], w1 = dinv[s1];
                    bf8_fma(a, w0, acc);
                    bf8_fma(b, w1, acc);
                }
                if (i < end) { int s = csr_src[i]; bf8_fma(in4[(size_t)s * 16 + col], dinv[s], acc); }
#pragma unroll
                for (int j = 0; j < 8; ++j) {
                    acc[j] += __shfl_xor(acc[j], 16, 64);
                    acc[j] += __shfl_xor(acc[j], 32, 64);
                }
            } else {                 // K==64: row = 8 uint4; 8 lanes/edge, 2-deep unroll
                int col = lane & 7;
                int i = beg + (lane >> 3);
                for (; i + 8 < end; i += 16) {
                    int s0 = csr_src[i], s1 = csr_src[i + 8];
                    uint4 a = in4[(size_t)s0 * 8 + col];
                    uint4 b = in4[(size_t)s1 * 8 + col];
                    float w0 = dinv[s0], w1 = dinv[s1];
                    bf8_fma(a, w0, acc);
                    bf8_fma(b, w1, acc);
                }
                if (i < end) { int s = csr_src[i]; bf8_fma(in4[(size_t)s * 8 + col], dinv[s], acc); }
#pragma unroll
                for (int j = 0; j < 8; ++j) {
                    acc[j] += __shfl_xor(acc[j], 8, 64);
                    acc[j] += __shfl_xor(acc[j], 16, 64);
                    acc[j] += __shfl_xor(acc[j], 32, 64);
                }
            }
        }
        // LDS write, swizzled: 16-way bank conflict on read otherwise (row stride % 128B == 0)
        if (lane < K / 8) {
            float dn = (node < n) ? dinv[node] : 0.f;
            uint4 o = pack_bf8(acc, dn);
            int off = row * K + ((lane * 8) ^ ((row & 7) << 3));
            *(uint4*)&As[off] = o;
        }
    }
    __syncthreads();

    f32x4 pacc[2] = {};
#pragma unroll
    for (int ks = 0; ks < KS; ++ks) {
        int off = lr * K + (((ks * 32) + lk * 8) ^ ((lr & 7) << 3));
        bf8_t a = *reinterpret_cast<const bf8_t*>(&As[off]);
#pragma unroll
        for (int f = 0; f < 2; ++f)
            pacc[f] = __builtin_amdgcn_mfma_f32_16x16x32_bf16(B[f][ks], a, pacc[f], 0, 0, 0);
    }

    int orow = base + lr;
    if (orow < n) {
#pragma unroll
        for (int f = 0; f < 2; ++f) {
            int c0 = w * 32 + f * 16 + lk * 4;
            float4 bv = *(const float4*)&bias[c0];
            float v0 = pacc[f][0] + bv.x, v1 = pacc[f][1] + bv.y;
            float v2 = pacc[f][2] + bv.z, v3 = pacc[f][3] + bv.w;
            if (RELU) {
                v0 = fmaxf(v0, 0.f); v1 = fmaxf(v1, 0.f);
                v2 = fmaxf(v2, 0.f); v3 = fmaxf(v3, 0.f);
            }
            if (BF16OUT) {
                uint2 o;
                o.x = (unsigned)f2bf(v0) | ((unsigned)f2bf(v1) << 16);
                o.y = (unsigned)f2bf(v2) | ((unsigned)f2bf(v3) << 16);
                *(uint2*)&((unsigned short*)outp)[(size_t)orow * 128 + c0] = o;
            } else {
                *(float4*)&((float*)outp)[(size_t)orow * 128 + c0] = make_float4(v0, v1, v2, v3);
            }
        }
    }
}

// ---------------- Pooling + head ----------------

__global__ void gstart_bs(const int* __restrict__ batch, int* __restrict__ gstart,
                          int n, int G) {
    int g = blockIdx.x * blockDim.x + threadIdx.x;
    if (g > G) return;
    int lo = 0, hi = n;
    while (lo < hi) {
        int mid = (lo + hi) >> 1;
        if (batch[mid] < g) lo = mid + 1; else hi = mid;
    }
    gstart[g] = lo;
}

#define PSPLIT 16
__global__ __launch_bounds__(256) void pool_part(
        const float* __restrict__ h, const int* __restrict__ gstart,
        float* __restrict__ part) {
    int g = blockIdx.x >> 4, sp = blockIdx.x & (PSPLIT - 1);
    int tid = threadIdx.x;
    int c = tid & 127, rs = tid >> 7;
    int beg = gstart[g], end = gstart[g + 1];
    int len = end - beg;
    int chunk = (len + PSPLIT - 1) >> 4;
    int r0 = beg + sp * chunk;
    int r1 = min(r0 + chunk, end);
    float acc = 0.f;
    for (int r = r0 + rs; r < r1; r += 2)
        acc += h[(size_t)r * 128 + c];
    __shared__ float buf[256];
    buf[tid] = acc;
    __syncthreads();
    if (rs == 0)
        part[(size_t)blockIdx.x * 128 + c] = buf[c] + buf[c + 128];
}

__global__ __launch_bounds__(128) void pool_final(
        const float* __restrict__ part, const int* __restrict__ gstart,
        float* __restrict__ gout) {
    int g = blockIdx.x;
    int c = threadIdx.x;
    float acc = 0.f;
#pragma unroll
    for (int sp = 0; sp < PSPLIT; ++sp)
        acc += part[((size_t)g * PSPLIT + sp) * 128 + c];
    int cnt = gstart[g + 1] - gstart[g];
    gout[g * 128 + c] = acc / fmaxf((float)cnt, 1.f);
}

__global__ void head_kernel(const float* __restrict__ g, const float* __restrict__ Wh,
                            const float* __restrict__ bh, float* __restrict__ out, int G) {
    int tid = blockIdx.x * blockDim.x + threadIdx.x;
    if (tid >= G * 8) return;
    int gi = tid >> 3, o = tid & 7;
    float acc = bh[o];
    for (int k = 0; k < 128; ++k)
        acc = fmaf(g[gi * 128 + k], Wh[k * 8 + o], acc);
    out[tid] = acc;
}

// ---------------- Launch ----------------

extern "C" void kernel_launch(void* const* d_in, const int* in_sizes, int n_in,
                              void* d_out, int out_size, void* d_ws, size_t ws_size,
                              hipStream_t stream) {
    const float* x  = (const float*)d_in[0];
    const float* W1 = (const float*)d_in[1];
    const float* b1 = (const float*)d_in[2];
    const float* W2 = (const float*)d_in[3];
    const float* b2 = (const float*)d_in[4];
    const float* W3 = (const float*)d_in[5];
    const float* b3 = (const float*)d_in[6];
    const float* Wh = (const float*)d_in[7];
    const float* bh = (const float*)d_in[8];
    const int* edge_index = (const int*)d_in[9];
    const int* batch = (const int*)d_in[10];
    (void)n_in; (void)ws_size;

    const int N = in_sizes[10];
    const int E = in_sizes[9] / 2;
    const int G = out_size / 8;
    const int* esrc = edge_index;
    const int* edst = edge_index + E;

    size_t off = 0;
    auto take = [&](size_t bytes) {
        void* p = (char*)d_ws + off;
        off += (bytes + 255) & ~(size_t)255;
        return p;
    };
    int*   deg      = (int*)take((size_t)N * 4);
    float* dinv     = (float*)take((size_t)N * 4);
    int*   row_ptr  = (int*)take((size_t)(N + 1) * 4);
    int*   rank     = (int*)take((size_t)E * 4);
    int*   csr_src  = (int*)take((size_t)(E + N) * 4);
    int*   bsum     = (int*)take(256 * 4);
    int*   boff     = (int*)take(256 * 4);
    int*   gstart   = (int*)take((size_t)(G + 1) * 4);
    float* part     = (float*)take((size_t)G * PSPLIT * 128 * 4);
    float* gpool    = (float*)take((size_t)G * 128 * 4);
    unsigned short* x16  = (unsigned short*)take((size_t)N * 64 * 2);
    unsigned short* h16a = (unsigned short*)take((size_t)N * 128 * 2);
    unsigned short* h16b = (unsigned short*)take((size_t)N * 128 * 2);
    unsigned short* Wt1  = (unsigned short*)take((size_t)128 * 64 * 2);
    unsigned short* Wt2  = (unsigned short*)take((size_t)128 * 128 * 2);
    unsigned short* Wt3  = (unsigned short*)take((size_t)128 * 128 * 2);
    float* bufA     = (float*)take((size_t)N * 128 * 4);

    int nblk = (N + 255) / 256;
    int fgrid = (N + 15) / 16;

    hipMemsetAsync(deg, 0, (size_t)N * 4, stream);

    deg_kernel<<<(E + 255) / 256, 256, 0, stream>>>(edst, deg, rank, E);
    scan_blocksum<<<nblk, 256, 0, stream>>>(deg, bsum, dinv, N);
    scan_offsets<<<1, 256, 0, stream>>>(bsum, boff, nblk);
    scan_rowptr<<<nblk, 256, 0, stream>>>(deg, boff, row_ptr, N);
    fill_kernel<<<(E + N + 255) / 256, 256, 0, stream>>>(esrc, edst, rank, row_ptr, csr_src, E, N);
    x2bf_kernel<<<(N * 64 / 8 + 255) / 256, 256, 0, stream>>>(x, (unsigned*)x16, N * 64 / 8);
    wt_all<<<(40960 + 255) / 256, 256, 0, stream>>>(W1, W2, W3, Wt1, Wt2, Wt3);

    // Fused layers (Agg(x)@W == Agg(x@W) used at layer 1)
    agg_gemm<64,  true,  true ><<<fgrid, 256, 0, stream>>>(x16,  Wt1, b1, h16a, row_ptr, csr_src, dinv, N);
    agg_gemm<128, true,  true ><<<fgrid, 256, 0, stream>>>(h16a, Wt2, b2, h16b, row_ptr, csr_src, dinv, N);
    agg_gemm<128, false, false><<<fgrid, 256, 0, stream>>>(h16b, Wt3, b3, bufA, row_ptr, csr_src, dinv, N);

    // Pool (batch sorted -> contiguous ranges): two-stage, then head
    gstart_bs<<<1, 256, 0, stream>>>(batch, gstart, N, G);
    pool_part<<<G * PSPLIT, 256, 0, stream>>>(bufA, gstart, part);
    pool_final<<<G, 128, 0, stream>>>(part, gstart, gpool);
    head_kernel<<<(G * 8 + 255) / 256, 256, 0, stream>>>(gpool, Wh, bh, (float*)d_out, G);
}